// Round 13
// baseline (196.387 us; speedup 1.0000x reference)
//
#include <hip/hip_runtime.h>

#define OUTC 512
#define INC 512
#define NTILE 4
#define TCOL 128   // OUTC / NTILE
#define LDA 72     // 64 + 8 ushort pad: conflict-free ds_read_b128
#define TPB 256

typedef __bf16 bf16x8 __attribute__((ext_vector_type(8)));
typedef float f32x4 __attribute__((ext_vector_type(4)));

static __device__ __forceinline__ unsigned short f2bf(float f) {
    unsigned u = __float_as_uint(f);
    unsigned r = u + 0x7fffu + ((u >> 16) & 1u);  // RNE
    return (unsigned short)(r >> 16);
}
static __device__ __forceinline__ float bflo(unsigned r) { return __uint_as_float(r << 16); }
static __device__ __forceinline__ float bfhi(unsigned r) { return __uint_as_float(r & 0xffff0000u); }
static __device__ __forceinline__ void acc8s(float* a, uint4 v, float n) {
    a[0] += n * bflo(v.x); a[1] += n * bfhi(v.x);
    a[2] += n * bflo(v.y); a[3] += n * bfhi(v.y);
    a[4] += n * bflo(v.z); a[5] += n * bfhi(v.z);
    a[6] += n * bflo(v.w); a[7] += n * bfhi(v.w);
}

// ---------- fused prep: dst-count | X->bf16 | W->bf16^T | temb ----------
__global__ __launch_bounds__(256) void k_prep(const float* __restrict__ x,
                                              const float* __restrict__ W,
                                              const float* __restrict__ t_emb,
                                              const float* __restrict__ Wt,
                                              const float* __restrict__ bt,
                                              const float* __restrict__ b,
                                              const int* __restrict__ dst,
                                              int* __restrict__ counts,
                                              unsigned short* __restrict__ xb,
                                              unsigned short* __restrict__ wtb,
                                              float* __restrict__ temb,
                                              int E, int CB, int XBB,
                                              int M, int Mpad, int TC) {
    __shared__ float smem[32 * 33];
    int bid = blockIdx.x;
    if (bid < CB) {
        int e = bid * 256 + threadIdx.x;
        if (e < E) atomicAdd(&counts[dst[e]], 1);
    } else if (bid < CB + XBB) {
        int idx = (bid - CB) * 256 + threadIdx.x;
        int row = idx >> 6;
        int kg = (idx & 63) * 8;
        ushort4 h0 = make_ushort4(0, 0, 0, 0), h1 = make_ushort4(0, 0, 0, 0);
        if (row < M) {
            float4 v0 = *(const float4*)(x + (size_t)row * INC + kg);
            float4 v1 = *(const float4*)(x + (size_t)row * INC + kg + 4);
            h0 = make_ushort4(f2bf(v0.x), f2bf(v0.y), f2bf(v0.z), f2bf(v0.w));
            h1 = make_ushort4(f2bf(v1.x), f2bf(v1.y), f2bf(v1.z), f2bf(v1.w));
        }
        *(ushort4*)(xb + (size_t)row * INC + kg) = h0;
        *(ushort4*)(xb + (size_t)row * INC + kg + 4) = h1;
    } else if (bid < CB + XBB + 256) {
        int b2 = bid - (CB + XBB);
        int bk = (b2 & 15) * 32, bn = (b2 >> 4) * 32;
        int tx = threadIdx.x & 31, ty = threadIdx.x >> 5;
        for (int r = ty; r < 32; r += 8)
            smem[r * 33 + tx] = W[(size_t)(bk + r) * OUTC + bn + tx];
        __syncthreads();
        for (int r = ty; r < 32; r += 8)
            wtb[(size_t)(bn + r) * INC + bk + tx] = f2bf(smem[tx * 33 + r]);
    } else {
        int j = bid - (CB + XBB + 256);
        int t = threadIdx.x;
        float p = 0.0f;
        for (int k = t; k < TC; k += 256) p += t_emb[k] * Wt[(size_t)k * OUTC + j];
        smem[t] = p;
        __syncthreads();
        for (int s = 128; s > 0; s >>= 1) {
            if (t < s) smem[t] += smem[t + s];
            __syncthreads();
        }
        if (t == 0) temb[j] = smem[0] + bt[j] + b[j];
    }
}

// ---------- fused: MFMA GEMM | wave bump-alloc ----------
__global__ __launch_bounds__(256) void k_ag(const unsigned short* __restrict__ xb,
                                            const unsigned short* __restrict__ wtb,
                                            unsigned short* __restrict__ xwb,
                                            const int* __restrict__ counts,
                                            int* __restrict__ row_start,
                                            int* __restrict__ cursor,
                                            float* __restrict__ dinv,
                                            int* __restrict__ allocCtr,
                                            int N, int Mpad) {
    __shared__ unsigned short la[128 * LDA];
    __shared__ unsigned short lb[64 * LDA];

    const int bid = blockIdx.x;
    const int tid = threadIdx.x;
    const int GB = (Mpad / 128) * 8;

    if (bid >= GB) {
        const int lane = tid & 63;
        const int gwave = ((bid - GB) * TPB + tid) >> 6;  // 0..159
        for (int c0 = gwave * 64; c0 < N; c0 += 160 * 64) {
            int d = c0 + lane;
            int deg = (d < N) ? counts[d] : 0;
            int incl = deg;
#pragma unroll
            for (int off = 1; off < 64; off <<= 1) {
                int v = __shfl_up(incl, off, 64);
                if (lane >= off) incl += v;
            }
            int wtot = __shfl(incl, 63, 64);
            int base = 0;
            if (lane == 63) base = atomicAdd(allocCtr, wtot);
            base = __shfl(base, 63, 64);
            if (d < N) {
                int rs = base + incl - deg;
                row_start[d] = rs;
                cursor[d] = rs;
                dinv[d] = rsqrtf((float)deg + 1.0f);
            }
        }
        return;
    }

    const int n0 = (bid & 7) * 64;
    const int m0 = (bid >> 3) * 128;
    const int lane = tid & 63;
    const int wave = tid >> 6;
    const int wm = wave * 32;
    const int l15 = lane & 15;
    const int k8 = (lane >> 4) * 8;

    f32x4 acc[2][4];
#pragma unroll
    for (int t = 0; t < 2; ++t)
#pragma unroll
        for (int u = 0; u < 4; ++u)
            acc[t][u] = (f32x4){0.f, 0.f, 0.f, 0.f};

    for (int k0 = 0; k0 < INC; k0 += 64) {
#pragma unroll
        for (int i = 0; i < 4; ++i) {
            int f = i * 256 + tid;
            int row = f >> 3, c = f & 7;
            uint4 v = *(const uint4*)(xb + (size_t)(m0 + row) * INC + k0 + c * 8);
            *(uint4*)(&la[row * LDA + c * 8]) = v;
        }
#pragma unroll
        for (int i = 0; i < 2; ++i) {
            int f = i * 256 + tid;
            int row = f >> 3, c = f & 7;
            uint4 v = *(const uint4*)(wtb + (size_t)(n0 + row) * INC + k0 + c * 8);
            *(uint4*)(&lb[row * LDA + c * 8]) = v;
        }
        __syncthreads();

#pragma unroll
        for (int kc = 0; kc < 64; kc += 32) {
            bf16x8 af0 = *(const bf16x8*)(&la[(wm + l15) * LDA + kc + k8]);
            bf16x8 af1 = *(const bf16x8*)(&la[(wm + 16 + l15) * LDA + kc + k8]);
#pragma unroll
            for (int u = 0; u < 4; ++u) {
                bf16x8 bfr = *(const bf16x8*)(&lb[(u * 16 + l15) * LDA + kc + k8]);
                acc[0][u] = __builtin_amdgcn_mfma_f32_16x16x32_bf16(af0, bfr, acc[0][u], 0, 0, 0);
                acc[1][u] = __builtin_amdgcn_mfma_f32_16x16x32_bf16(af1, bfr, acc[1][u], 0, 0, 0);
            }
        }
        __syncthreads();
    }

    const int rbase = (lane >> 4) * 4;
#pragma unroll
    for (int t = 0; t < 2; ++t)
#pragma unroll
        for (int u = 0; u < 4; ++u) {
            int gcol = n0 + u * 16 + l15;
            unsigned short* p = xwb + (size_t)(gcol >> 7) * Mpad * TCOL + (gcol & 127);
#pragma unroll
            for (int r = 0; r < 4; ++r) {
                int grow = m0 + wm + t * 16 + rbase + r;  // < Mpad
                p[(size_t)grow * TCOL] = f2bf(acc[t][u][r]);
            }
        }
}

// ---------- CSR scatter: pack (src, dinv[src]) ----------
__global__ void k_scatter(const int* __restrict__ src, const int* __restrict__ dst,
                          const float* __restrict__ dinv,
                          int* __restrict__ cursor, int2* __restrict__ epk, int E) {
    int e = blockIdx.x * blockDim.x + threadIdx.x;
    if (e < E) {
        int s = src[e];
        int d = dst[e];
        int pos = atomicAdd(&cursor[d], 1);
        epk[pos] = make_int2(s, __float_as_int(dinv[s]));
    }
}

// ---------- XCD-pinned column-tiled gather (R12-identical, idempotent) ----------
__global__ __launch_bounds__(256) void k_gather(const int2* __restrict__ epk,
                                                const int* __restrict__ row_start,
                                                const int* __restrict__ counts,
                                                const unsigned short* __restrict__ xwb,
                                                const float* __restrict__ dinv,
                                                const float* __restrict__ temb,
                                                float* __restrict__ out, int N, int Mpad) {
    const int bid = blockIdx.x;
    const int tile = (bid & 7) >> 1;
    const int node = (bid >> 3) * 8 + (bid & 1) * 4 + (threadIdx.x >> 6);
    if (node >= N) return;
    const int lane = threadIdx.x & 63;
    const int slot = lane >> 4;
    const int c8 = (lane & 15) * 8;
    const unsigned short* basep = xwb + (size_t)tile * Mpad * TCOL + c8;

    float a[8] = {0.f, 0.f, 0.f, 0.f, 0.f, 0.f, 0.f, 0.f};
    const int s0 = row_start[node];
    const int s1 = s0 + counts[node];
    int i = s0;
    for (; i + 8 <= s1; i += 8) {
        int2 eA = epk[i + slot];
        int2 eB = epk[i + 4 + slot];
        float nA = __int_as_float(eA.y);
        float nB = __int_as_float(eB.y);
        uint4 vA = *(const uint4*)(basep + (size_t)eA.x * TCOL);
        uint4 vB = *(const uint4*)(basep + (size_t)eB.x * TCOL);
        acc8s(a, vA, nA);
        acc8s(a, vB, nB);
    }
    for (; i < s1; i += 4) {
        int idx = i + slot;
        int sA = node;
        float nA = 0.f;
        if (idx < s1) {
            int2 e = epk[idx];
            sA = e.x;
            nA = __int_as_float(e.y);
        }
        uint4 v = *(const uint4*)(basep + (size_t)sA * TCOL);
        acc8s(a, v, nA);
    }
#pragma unroll
    for (int k = 0; k < 8; ++k) {
        a[k] += __shfl_xor(a[k], 16, 64);
        a[k] += __shfl_xor(a[k], 32, 64);
    }
    const float di = dinv[node];
    {
        uint4 v = *(const uint4*)(basep + (size_t)node * TCOL);
        acc8s(a, v, di);
    }
    if (slot < 2) {
        const int gc = tile * TCOL + c8 + slot * 4;
        float4 tv = *(const float4*)(temb + gc);
        float4 o;
        o.x = di * a[slot * 4 + 0] + tv.x;
        o.y = di * a[slot * 4 + 1] + tv.y;
        o.z = di * a[slot * 4 + 2] + tv.z;
        o.w = di * a[slot * 4 + 3] + tv.w;
        *(float4*)(out + (size_t)node * OUTC + gc) = o;
    }
}

extern "C" void kernel_launch(void* const* d_in, const int* in_sizes, int n_in,
                              void* d_out, int out_size, void* d_ws, size_t ws_size,
                              hipStream_t stream) {
    const float* x     = (const float*)d_in[0];
    const float* t_emb = (const float*)d_in[1];
    const int*   ei    = (const int*)d_in[2];
    const float* W     = (const float*)d_in[3];
    const float* b     = (const float*)d_in[4];
    const float* Wt    = (const float*)d_in[5];
    const float* bt    = (const float*)d_in[6];
    float* out = (float*)d_out;

    const int N  = in_sizes[0] / INC;    // 10000
    const int E  = in_sizes[2] / 2;      // 160000
    const int TC = in_sizes[1];          // 256
    const int Mpad = (N + 127) & ~127;   // 10112

    char* ws = (char*)d_ws;
    size_t off = 0;
    unsigned short* xb  = (unsigned short*)(ws + off); off += (size_t)Mpad * INC * 2;
    unsigned short* xwb = (unsigned short*)(ws + off); off += (size_t)Mpad * OUTC * 2;
    unsigned short* wtb = (unsigned short*)(ws + off); off += (size_t)INC * OUTC * 2;
    float* dinv = (float*)(ws + off);      off += ((size_t)N * 4 + 255) & ~(size_t)255;
    int* counts = (int*)(ws + off);        off += ((size_t)(N + 1) * 4 + 255) & ~(size_t)255;
    int* allocCtr = counts + N;
    int* row_start = (int*)(ws + off);     off += ((size_t)N * 4 + 255) & ~(size_t)255;
    int* cursor = (int*)(ws + off);        off += ((size_t)N * 4 + 255) & ~(size_t)255;
    int2* epk = (int2*)(ws + off);         off += ((size_t)(E + 64) * 8 + 255) & ~(size_t)255;
    float* temb = (float*)(ws + off);      off += OUTC * 4;

    const int* srcIdx = ei;
    const int* dstIdx = ei + E;

    const int CB  = (E + 255) / 256;        // 625
    const int XBB = Mpad * (INC / 8) / 256; // 2528
    const int GB  = (Mpad / 128) * 8;       // 632

    hipMemsetAsync(counts, 0, (size_t)(N + 1) * sizeof(int), stream);
    k_prep<<<CB + XBB + 256 + OUTC, TPB, 0, stream>>>(x, W, t_emb, Wt, bt, b, dstIdx,
                                                      counts, xb, wtb, temb,
                                                      E, CB, XBB, N, Mpad, TC);
    k_ag<<<GB + 40, TPB, 0, stream>>>(xb, wtb, xwb, counts, row_start, cursor,
                                      dinv, allocCtr, N, Mpad);
    k_scatter<<<(E + 255) / 256, TPB, 0, stream>>>(srcIdx, dstIdx, dinv, cursor, epk, E);

    const int gather_blocks = ((N + 7) / 8) * 8;
    // PROBE: gather launched 3x (idempotent). dur_us = base + 2*g -> g measured.
    k_gather<<<gather_blocks, TPB, 0, stream>>>(epk, row_start, counts, xwb, dinv,
                                                temb, out, N, Mpad);
    k_gather<<<gather_blocks, TPB, 0, stream>>>(epk, row_start, counts, xwb, dinv,
                                                temb, out, N, Mpad);
    k_gather<<<gather_blocks, TPB, 0, stream>>>(epk, row_start, counts, xwb, dinv,
                                                temb, out, N, Mpad);
}

// Round 14
// 148.028 us; speedup vs baseline: 1.3267x; 1.3267x over previous
//
#include <hip/hip_runtime.h>

#define OUTC 512
#define INC 512
#define NTILE 4
#define TCOL 128   // OUTC / NTILE
#define LDA 72     // 64 + 8 ushort pad: conflict-free ds_read_b128
#define TPB 256

typedef __bf16 bf16x8 __attribute__((ext_vector_type(8)));
typedef float f32x4 __attribute__((ext_vector_type(4)));

static __device__ __forceinline__ unsigned short f2bf(float f) {
    unsigned u = __float_as_uint(f);
    unsigned r = u + 0x7fffu + ((u >> 16) & 1u);  // RNE
    return (unsigned short)(r >> 16);
}
static __device__ __forceinline__ float bflo(unsigned r) { return __uint_as_float(r << 16); }
static __device__ __forceinline__ float bfhi(unsigned r) { return __uint_as_float(r & 0xffff0000u); }
static __device__ __forceinline__ void acc8s(float* a, uint4 v, float n) {
    a[0] += n * bflo(v.x); a[1] += n * bfhi(v.x);
    a[2] += n * bflo(v.y); a[3] += n * bfhi(v.y);
    a[4] += n * bflo(v.z); a[5] += n * bfhi(v.z);
    a[6] += n * bflo(v.w); a[7] += n * bfhi(v.w);
}

// ---------- tiny zero kernel (replaces hipMemsetAsync -> rocclr fill, which
// showed a ~45 us fixed cost in rocprof even at 15 KB) ----------
__global__ void k_zero(int* __restrict__ p, int n) {
    int i = blockIdx.x * 256 + threadIdx.x;
    if (i < n) p[i] = 0;
}

// ---------- fused prep: dst-count | X->bf16 | W->bf16^T | temb ----------
__global__ __launch_bounds__(256) void k_prep(const float* __restrict__ x,
                                              const float* __restrict__ W,
                                              const float* __restrict__ t_emb,
                                              const float* __restrict__ Wt,
                                              const float* __restrict__ bt,
                                              const float* __restrict__ b,
                                              const int* __restrict__ dst,
                                              int* __restrict__ counts,
                                              unsigned short* __restrict__ xb,
                                              unsigned short* __restrict__ wtb,
                                              float* __restrict__ temb,
                                              int E, int CB, int XBB,
                                              int M, int Mpad, int TC) {
    __shared__ float smem[32 * 33];
    int bid = blockIdx.x;
    if (bid < CB) {
        int e = bid * 256 + threadIdx.x;
        if (e < E) atomicAdd(&counts[dst[e]], 1);
    } else if (bid < CB + XBB) {
        int idx = (bid - CB) * 256 + threadIdx.x;
        int row = idx >> 6;
        int kg = (idx & 63) * 8;
        ushort4 h0 = make_ushort4(0, 0, 0, 0), h1 = make_ushort4(0, 0, 0, 0);
        if (row < M) {
            float4 v0 = *(const float4*)(x + (size_t)row * INC + kg);
            float4 v1 = *(const float4*)(x + (size_t)row * INC + kg + 4);
            h0 = make_ushort4(f2bf(v0.x), f2bf(v0.y), f2bf(v0.z), f2bf(v0.w));
            h1 = make_ushort4(f2bf(v1.x), f2bf(v1.y), f2bf(v1.z), f2bf(v1.w));
        }
        *(ushort4*)(xb + (size_t)row * INC + kg) = h0;
        *(ushort4*)(xb + (size_t)row * INC + kg + 4) = h1;
    } else if (bid < CB + XBB + 256) {
        int b2 = bid - (CB + XBB);
        int bk = (b2 & 15) * 32, bn = (b2 >> 4) * 32;
        int tx = threadIdx.x & 31, ty = threadIdx.x >> 5;
        for (int r = ty; r < 32; r += 8)
            smem[r * 33 + tx] = W[(size_t)(bk + r) * OUTC + bn + tx];
        __syncthreads();
        for (int r = ty; r < 32; r += 8)
            wtb[(size_t)(bn + r) * INC + bk + tx] = f2bf(smem[tx * 33 + r]);
    } else {
        int j = bid - (CB + XBB + 256);
        int t = threadIdx.x;
        float p = 0.0f;
        for (int k = t; k < TC; k += 256) p += t_emb[k] * Wt[(size_t)k * OUTC + j];
        smem[t] = p;
        __syncthreads();
        for (int s = 128; s > 0; s >>= 1) {
            if (t < s) smem[t] += smem[t + s];
            __syncthreads();
        }
        if (t == 0) temb[j] = smem[0] + bt[j] + b[j];
    }
}

// ---------- fused: MFMA GEMM | wave bump-alloc ----------
__global__ __launch_bounds__(256) void k_ag(const unsigned short* __restrict__ xb,
                                            const unsigned short* __restrict__ wtb,
                                            unsigned short* __restrict__ xwb,
                                            const int* __restrict__ counts,
                                            int* __restrict__ row_start,
                                            int* __restrict__ cursor,
                                            float* __restrict__ dinv,
                                            int* __restrict__ allocCtr,
                                            int N, int Mpad) {
    __shared__ unsigned short la[128 * LDA];
    __shared__ unsigned short lb[64 * LDA];

    const int bid = blockIdx.x;
    const int tid = threadIdx.x;
    const int GB = (Mpad / 128) * 8;

    if (bid >= GB) {
        const int lane = tid & 63;
        const int gwave = ((bid - GB) * TPB + tid) >> 6;  // 0..159
        for (int c0 = gwave * 64; c0 < N; c0 += 160 * 64) {
            int d = c0 + lane;
            int deg = (d < N) ? counts[d] : 0;
            int incl = deg;
#pragma unroll
            for (int off = 1; off < 64; off <<= 1) {
                int v = __shfl_up(incl, off, 64);
                if (lane >= off) incl += v;
            }
            int wtot = __shfl(incl, 63, 64);
            int base = 0;
            if (lane == 63) base = atomicAdd(allocCtr, wtot);
            base = __shfl(base, 63, 64);
            if (d < N) {
                int rs = base + incl - deg;
                row_start[d] = rs;
                cursor[d] = rs;
                dinv[d] = rsqrtf((float)deg + 1.0f);
            }
        }
        return;
    }

    const int n0 = (bid & 7) * 64;
    const int m0 = (bid >> 3) * 128;
    const int lane = tid & 63;
    const int wave = tid >> 6;
    const int wm = wave * 32;
    const int l15 = lane & 15;
    const int k8 = (lane >> 4) * 8;

    f32x4 acc[2][4];
#pragma unroll
    for (int t = 0; t < 2; ++t)
#pragma unroll
        for (int u = 0; u < 4; ++u)
            acc[t][u] = (f32x4){0.f, 0.f, 0.f, 0.f};

    for (int k0 = 0; k0 < INC; k0 += 64) {
#pragma unroll
        for (int i = 0; i < 4; ++i) {
            int f = i * 256 + tid;
            int row = f >> 3, c = f & 7;
            uint4 v = *(const uint4*)(xb + (size_t)(m0 + row) * INC + k0 + c * 8);
            *(uint4*)(&la[row * LDA + c * 8]) = v;
        }
#pragma unroll
        for (int i = 0; i < 2; ++i) {
            int f = i * 256 + tid;
            int row = f >> 3, c = f & 7;
            uint4 v = *(const uint4*)(wtb + (size_t)(n0 + row) * INC + k0 + c * 8);
            *(uint4*)(&lb[row * LDA + c * 8]) = v;
        }
        __syncthreads();

#pragma unroll
        for (int kc = 0; kc < 64; kc += 32) {
            bf16x8 af0 = *(const bf16x8*)(&la[(wm + l15) * LDA + kc + k8]);
            bf16x8 af1 = *(const bf16x8*)(&la[(wm + 16 + l15) * LDA + kc + k8]);
#pragma unroll
            for (int u = 0; u < 4; ++u) {
                bf16x8 bfr = *(const bf16x8*)(&lb[(u * 16 + l15) * LDA + kc + k8]);
                acc[0][u] = __builtin_amdgcn_mfma_f32_16x16x32_bf16(af0, bfr, acc[0][u], 0, 0, 0);
                acc[1][u] = __builtin_amdgcn_mfma_f32_16x16x32_bf16(af1, bfr, acc[1][u], 0, 0, 0);
            }
        }
        __syncthreads();
    }

    const int rbase = (lane >> 4) * 4;
#pragma unroll
    for (int t = 0; t < 2; ++t)
#pragma unroll
        for (int u = 0; u < 4; ++u) {
            int gcol = n0 + u * 16 + l15;
            unsigned short* p = xwb + (size_t)(gcol >> 7) * Mpad * TCOL + (gcol & 127);
#pragma unroll
            for (int r = 0; r < 4; ++r) {
                int grow = m0 + wm + t * 16 + rbase + r;  // < Mpad
                p[(size_t)grow * TCOL] = f2bf(acc[t][u][r]);
            }
        }
}

// ---------- CSR scatter: pack (src, dinv[src]) ----------
__global__ void k_scatter(const int* __restrict__ src, const int* __restrict__ dst,
                          const float* __restrict__ dinv,
                          int* __restrict__ cursor, int2* __restrict__ epk, int E) {
    int e = blockIdx.x * blockDim.x + threadIdx.x;
    if (e < E) {
        int s = src[e];
        int d = dst[e];
        int pos = atomicAdd(&cursor[d], 1);
        epk[pos] = make_int2(s, __float_as_int(dinv[s]));
    }
}

// ---------- XCD-pinned column-tiled gather ----------
__global__ __launch_bounds__(256) void k_gather(const int2* __restrict__ epk,
                                                const int* __restrict__ row_start,
                                                const int* __restrict__ counts,
                                                const unsigned short* __restrict__ xwb,
                                                const float* __restrict__ dinv,
                                                const float* __restrict__ temb,
                                                float* __restrict__ out, int N, int Mpad) {
    const int bid = blockIdx.x;
    const int tile = (bid & 7) >> 1;
    const int node = (bid >> 3) * 8 + (bid & 1) * 4 + (threadIdx.x >> 6);
    if (node >= N) return;
    const int lane = threadIdx.x & 63;
    const int slot = lane >> 4;
    const int c8 = (lane & 15) * 8;
    const unsigned short* basep = xwb + (size_t)tile * Mpad * TCOL + c8;

    float a[8] = {0.f, 0.f, 0.f, 0.f, 0.f, 0.f, 0.f, 0.f};
    const int s0 = row_start[node];
    const int s1 = s0 + counts[node];
    int i = s0;
    for (; i + 8 <= s1; i += 8) {
        int2 eA = epk[i + slot];
        int2 eB = epk[i + 4 + slot];
        float nA = __int_as_float(eA.y);
        float nB = __int_as_float(eB.y);
        uint4 vA = *(const uint4*)(basep + (size_t)eA.x * TCOL);
        uint4 vB = *(const uint4*)(basep + (size_t)eB.x * TCOL);
        acc8s(a, vA, nA);
        acc8s(a, vB, nB);
    }
    for (; i < s1; i += 4) {
        int idx = i + slot;
        int sA = node;
        float nA = 0.f;
        if (idx < s1) {
            int2 e = epk[idx];
            sA = e.x;
            nA = __int_as_float(e.y);
        }
        uint4 v = *(const uint4*)(basep + (size_t)sA * TCOL);
        acc8s(a, v, nA);
    }
#pragma unroll
    for (int k = 0; k < 8; ++k) {
        a[k] += __shfl_xor(a[k], 16, 64);
        a[k] += __shfl_xor(a[k], 32, 64);
    }
    const float di = dinv[node];
    {
        uint4 v = *(const uint4*)(basep + (size_t)node * TCOL);
        acc8s(a, v, di);
    }
    if (slot < 2) {
        const int gc = tile * TCOL + c8 + slot * 4;
        float4 tv = *(const float4*)(temb + gc);
        float4 o;
        o.x = di * a[slot * 4 + 0] + tv.x;
        o.y = di * a[slot * 4 + 1] + tv.y;
        o.z = di * a[slot * 4 + 2] + tv.z;
        o.w = di * a[slot * 4 + 3] + tv.w;
        *(float4*)(out + (size_t)node * OUTC + gc) = o;
    }
}

extern "C" void kernel_launch(void* const* d_in, const int* in_sizes, int n_in,
                              void* d_out, int out_size, void* d_ws, size_t ws_size,
                              hipStream_t stream) {
    const float* x     = (const float*)d_in[0];
    const float* t_emb = (const float*)d_in[1];
    const int*   ei    = (const int*)d_in[2];
    const float* W     = (const float*)d_in[3];
    const float* b     = (const float*)d_in[4];
    const float* Wt    = (const float*)d_in[5];
    const float* bt    = (const float*)d_in[6];
    float* out = (float*)d_out;

    const int N  = in_sizes[0] / INC;    // 10000
    const int E  = in_sizes[2] / 2;      // 160000
    const int TC = in_sizes[1];          // 256
    const int Mpad = (N + 127) & ~127;   // 10112

    char* ws = (char*)d_ws;
    size_t off = 0;
    unsigned short* xb  = (unsigned short*)(ws + off); off += (size_t)Mpad * INC * 2;
    unsigned short* xwb = (unsigned short*)(ws + off); off += (size_t)Mpad * OUTC * 2;
    unsigned short* wtb = (unsigned short*)(ws + off); off += (size_t)INC * OUTC * 2;
    float* dinv = (float*)(ws + off);      off += ((size_t)N * 4 + 255) & ~(size_t)255;
    int* counts = (int*)(ws + off);        off += ((size_t)(N + 1) * 4 + 255) & ~(size_t)255;
    int* allocCtr = counts + N;
    int* row_start = (int*)(ws + off);     off += ((size_t)N * 4 + 255) & ~(size_t)255;
    int* cursor = (int*)(ws + off);        off += ((size_t)N * 4 + 255) & ~(size_t)255;
    int2* epk = (int2*)(ws + off);         off += ((size_t)(E + 64) * 8 + 255) & ~(size_t)255;
    float* temb = (float*)(ws + off);      off += OUTC * 4;

    const int* srcIdx = ei;
    const int* dstIdx = ei + E;

    const int CB  = (E + 255) / 256;        // 625
    const int XBB = Mpad * (INC / 8) / 256; // 2528
    const int GB  = (Mpad / 128) * 8;       // 632

    k_zero<<<(N + 1 + 255) / 256, TPB, 0, stream>>>(counts, N + 1);  // counts + allocCtr
    k_prep<<<CB + XBB + 256 + OUTC, TPB, 0, stream>>>(x, W, t_emb, Wt, bt, b, dstIdx,
                                                      counts, xb, wtb, temb,
                                                      E, CB, XBB, N, Mpad, TC);
    k_ag<<<GB + 40, TPB, 0, stream>>>(xb, wtb, xwb, counts, row_start, cursor,
                                      dinv, allocCtr, N, Mpad);
    k_scatter<<<(E + 255) / 256, TPB, 0, stream>>>(srcIdx, dstIdx, dinv, cursor, epk, E);

    const int gather_blocks = ((N + 7) / 8) * 8;
    k_gather<<<gather_blocks, TPB, 0, stream>>>(epk, row_start, counts, xwb, dinv,
                                                temb, out, N, Mpad);
}